// Round 10
// baseline (1269.379 us; speedup 1.0000x reference)
//
#include <hip/hip_runtime.h>
#include <stdint.h>

#define N 8192
#define DIM 1024
#define EPSF 1e-8f
#define NBLK 32           // 8192/256
#define NTRI 528          // NBLK*(NBLK+1)/2
#define NKT 32            // K-tiles of 32: 1024/32

typedef __attribute__((ext_vector_type(4))) float f32x4;
typedef __attribute__((ext_vector_type(8))) short s16x8;

// ---- helpers ----
__device__ inline unsigned short f2bf(float f) {
  unsigned u = __float_as_uint(f);
  unsigned r = (u + 0x7FFFu + ((u >> 16) & 1u)) >> 16;
  return (unsigned short)r;
}

__device__ inline unsigned encf(float f) {
  unsigned u = __float_as_uint(f);
  return (u & 0x80000000u) ? ~u : (u | 0x80000000u);
}

// ws layout:
//   [0, 16MiB)       : xb   bf16 normalized rows, row-major 8192x1024 (ushort)
//   [16777216,+32KiB): invn fp32 per-row 1/max(norm,eps)
//   [16809984,+64KiB): keys u64 packed (enc(sim)<<32)|~col
//   [16875520,+32KiB): part fp32 per-row log(dist+eps)
#define XB_OFF   0
#define INV_OFF  16777216
#define KEY_OFF  16809984
#define PART_OFF 16875520

// ---------------- kernel 1: normalize + init ----------------
__global__ __launch_bounds__(256)
void k_norm(const float* __restrict__ x, unsigned short* __restrict__ xb,
            float* __restrict__ invn, unsigned long long* __restrict__ keys) {
  int row = blockIdx.x, t = threadIdx.x;
  const float4* xr = (const float4*)(x + (size_t)row * DIM);
  float4 v = xr[t];
  float ss = v.x * v.x + v.y * v.y + v.z * v.z + v.w * v.w;
#pragma unroll
  for (int o = 32; o > 0; o >>= 1) ss += __shfl_down(ss, o, 64);
  __shared__ float red[4];
  __shared__ float sinv;
  if ((t & 63) == 0) red[t >> 6] = ss;
  __syncthreads();
  if (t == 0) {
    float s = red[0] + red[1] + red[2] + red[3];
    float inv = 1.0f / fmaxf(sqrtf(s), EPSF);
    sinv = inv;
    invn[row] = inv;
    keys[row] = 0ull;           // any sim >= -1 encodes > 0
  }
  __syncthreads();
  float inv = sinv;
  ushort4 o4;
  o4.x = f2bf(v.x * inv);
  o4.y = f2bf(v.y * inv);
  o4.z = f2bf(v.z * inv);
  o4.w = f2bf(v.w * inv);
  ((ushort4*)(xb + (size_t)row * DIM))[t] = o4;
}

// ---------------- kernel 2: sim GEMM + argmax (256^2, 2-slot dbuf, 2 blocks/CU) ----------------
// 512 threads = 8 waves (2Mx4N), per-wave 128x64 output, BK=32.
// LDS: 2 slots A + 2 slots B = 64 KiB dynamic -> TWO blocks per CU. Blocks are
// barrier-independent, so one block's LDS-read phase overlaps the other's MFMA
// phase (m114 mechanism) -- attacks the read->MFMA lockstep serialization that
// capped r9 at 18% MfmaUtil with 1 block/CU.
// T3 minimum-2-phase tile body: {STAGE(t+1, other slot); 12 ds_read (slot t&1);
// 32 MFMA (stage latency hides under it); vmcnt(0); s_barrier}.
// Ledger: stage(t+1) writes slot (t+1)&1, last read during tile t-1, retired
// before end-of-(t-1) barrier. vmcnt(0) before barrier proves t+1 landed.
__global__ __launch_bounds__(512, 4)
void k_sim(const unsigned short* __restrict__ xb, unsigned long long* __restrict__ keys) {
  extern __shared__ unsigned short lds_us[];   // A: [0,16384) ushorts, B: [16384,32768)

  int b = blockIdx.x;
  int bi = (int)((65.0f - sqrtf(4225.0f - 8.0f * (float)b)) * 0.5f);
  while ((bi + 1) * (65 - (bi + 1)) / 2 <= b) ++bi;
  while (bi * (65 - bi) / 2 > b) --bi;
  int bj = bi + (b - bi * (65 - bi) / 2);

  const int t = threadIdx.x, lane = t & 63, wv = t >> 6;
  const int wr = wv >> 2, wc = wv & 3;       // wave -> (2M x 4N) grid
  const int hi = lane >> 4, lo = lane & 15;
  const int rowBase = bi * 256, colBase = bj * 256;

  const unsigned short* gA = xb + (size_t)rowBase * DIM;
  const unsigned short* gB = xb + (size_t)colBase * DIM;

  // staging constants: chunk ci = j*512 + wv*64 + lane; row r=ci>>2, slot s=ci&3;
  // source chunk c = s ^ ((r>>1)&3)  -> lane-only: (lane&3)^((lane>>3)&3)
  const int sg = (lane & 3) ^ ((lane >> 3) & 3);
  const size_t soA0 = (size_t)(wv * 16 + (lane >> 2)) * DIM + sg * 8;   // j=0 rows 0..127
  const size_t soA1 = soA0 + (size_t)128 * DIM;                         // j=1 rows 128..255
  const int ldsA0 = wv * 512;          // uniform per wave (ushort offset)
  const int ldsA1 = 4096 + wv * 512;

// stage K-tile -> ring slot SLOT (compile-time const), k-offset KO (elements)
#define STAGE_SLOT(SLOT, KO) do {                                                    \
    const size_t ko_ = (size_t)(KO);                                                 \
    unsigned short* Ab_ = lds_us + (SLOT) * 8192;                                    \
    unsigned short* Bb_ = lds_us + 16384 + (SLOT) * 8192;                            \
    __builtin_amdgcn_global_load_lds(                                                \
        (const __attribute__((address_space(1))) void*)(gA + soA0 + ko_),            \
        (__attribute__((address_space(3))) void*)(Ab_ + ldsA0), 16, 0, 0);           \
    __builtin_amdgcn_global_load_lds(                                                \
        (const __attribute__((address_space(1))) void*)(gA + soA1 + ko_),            \
        (__attribute__((address_space(3))) void*)(Ab_ + ldsA1), 16, 0, 0);           \
    __builtin_amdgcn_global_load_lds(                                                \
        (const __attribute__((address_space(1))) void*)(gB + soA0 + ko_),            \
        (__attribute__((address_space(3))) void*)(Bb_ + ldsA0), 16, 0, 0);           \
    __builtin_amdgcn_global_load_lds(                                                \
        (const __attribute__((address_space(1))) void*)(gB + soA1 + ko_),            \
        (__attribute__((address_space(3))) void*)(Bb_ + ldsA1), 16, 0, 0);           \
  } while (0)

#define WB0 do { asm volatile("s_waitcnt vmcnt(0)" ::: "memory"); __builtin_amdgcn_s_barrier(); } while (0)

// tile body: STAGE first (T3 recipe) -> reads (slot RS, const) -> MFMA -> wait+barrier
#define TILE(RS, STAGE_EXPR, WAIT_STMT) do {                                         \
    STAGE_EXPR;                                                                      \
    const unsigned short* Ab = lds_us + (RS) * 8192;                                 \
    const unsigned short* Bb = lds_us + 16384 + (RS) * 8192;                         \
    s16x8 af[8], bfr[4];                                                             \
    _Pragma("unroll")                                                                \
    for (int mi = 0; mi < 8; ++mi) {                                                 \
      int r = wr * 128 + mi * 16 + lo;                                               \
      af[mi] = *(const s16x8*)(Ab + r * 32 + chux);                                  \
    }                                                                                \
    _Pragma("unroll")                                                                \
    for (int ni = 0; ni < 4; ++ni) {                                                 \
      int r = wc * 64 + ni * 16 + lo;                                                \
      bfr[ni] = *(const s16x8*)(Bb + r * 32 + chux);                                 \
    }                                                                                \
    __builtin_amdgcn_s_setprio(1);                                                   \
    _Pragma("unroll")                                                                \
    for (int mi = 0; mi < 8; ++mi)                                                   \
      _Pragma("unroll")                                                              \
      for (int ni = 0; ni < 4; ++ni)                                                 \
        acc[mi][ni] = __builtin_amdgcn_mfma_f32_16x16x32_bf16(af[mi], bfr[ni],       \
                                                              acc[mi][ni], 0, 0, 0); \
    __builtin_amdgcn_s_setprio(0);                                                   \
    WAIT_STMT;                                                                       \
  } while (0)

  const f32x4 fzero = {0.f, 0.f, 0.f, 0.f};
  f32x4 acc[8][4];
#pragma unroll
  for (int i = 0; i < 8; ++i)
#pragma unroll
    for (int j = 0; j < 4; ++j) acc[i][j] = fzero;

  // fragment-read swizzled chunk: ch = hi ^ ((r>>1)&3) with r=16m+lo -> lane-only
  const int chux = (hi ^ ((lo >> 1) & 3)) * 8;

  // ---- prologue: stage tile 0 into slot 0 ----
  STAGE_SLOT(0, 0);
  WB0;

  // ---- main: tiles 0..29 as const-slot pairs ----
  for (int kb = 0; kb < 30; kb += 2) {
    TILE(0, STAGE_SLOT(1, (kb + 1) * 32), WB0);
    TILE(1, STAGE_SLOT(0, (kb + 2) * 32), WB0);
  }
  // ---- tail: tiles 30, 31 ----
  TILE(0, STAGE_SLOT(1, 31 * 32), WB0);   // tile 30, stages tile 31
  TILE(1, (void)0, (void)0);              // tile 31

#undef TILE
#undef STAGE_SLOT
#undef WB0

  // ---- per-row argmax (C layout: col=lane&15, row=(lane>>4)*4+reg) ----
#pragma unroll
  for (int am = 0; am < 8; ++am) {
#pragma unroll
    for (int reg = 0; reg < 4; ++reg) {
      int grow = rowBase + wr * 128 + am * 16 + hi * 4 + reg;
      float best = -10.0f;
      int bcol = 0;
#pragma unroll
      for (int ni = 0; ni < 4; ++ni) {
        int gcol = colBase + wc * 64 + ni * 16 + lo;
        float v = acc[am][ni][reg];
        v = (gcol == grow) ? -10.0f : v;   // mask diagonal
        if (v > best || (v == best && gcol < bcol)) { best = v; bcol = gcol; }
      }
#pragma unroll
      for (int m = 1; m < 16; m <<= 1) {
        float ov = __shfl_xor(best, m, 64);
        int oc = __shfl_xor(bcol, m, 64);
        if (ov > best || (ov == best && oc < bcol)) { best = ov; bcol = oc; }
      }
      if (lo == 0) {
        unsigned long long key = ((unsigned long long)encf(best) << 32) | (unsigned)(~bcol);
        atomicMax(&keys[grow], key);
      }
    }
  }

  // ---- per-col argmax (symmetric contribution), off-diagonal blocks only ----
  if (bi != bj) {
#pragma unroll
    for (int ni = 0; ni < 4; ++ni) {
      int gcol = colBase + wc * 64 + ni * 16 + lo;
      float best = -10.0f;
      int brow = 0;
#pragma unroll
      for (int am = 0; am < 8; ++am)
#pragma unroll
        for (int reg = 0; reg < 4; ++reg) {
          int grow = rowBase + wr * 128 + am * 16 + hi * 4 + reg;
          float v = acc[am][ni][reg];
          if (v > best || (v == best && grow < brow)) { best = v; brow = grow; }
        }
#pragma unroll
      for (int m = 16; m < 64; m <<= 1) {
        float ov = __shfl_xor(best, m, 64);
        int oc = __shfl_xor(brow, m, 64);
        if (ov > best || (ov == best && oc < brow)) { best = ov; brow = oc; }
      }
      if (hi == 0) {
        unsigned long long key = ((unsigned long long)encf(best) << 32) | (unsigned)(~brow);
        atomicMax(&keys[gcol], key);
      }
    }
  }
}

// ---------------- kernel 3: exact fp32 distance -> per-row partial ----------------
__global__ __launch_bounds__(256)
void k_dist(const float* __restrict__ x, const float* __restrict__ invn,
            const unsigned long long* __restrict__ keys, float* __restrict__ part) {
  int row = blockIdx.x, t = threadIdx.x;
  unsigned long long key = keys[row];
  int nb = (int)(~(unsigned)key);       // decode ~col
  float ia = invn[row], ib = invn[nb];
  float4 a = ((const float4*)(x + (size_t)row * DIM))[t];
  float4 b = ((const float4*)(x + (size_t)nb * DIM))[t];
  float d0 = a.x * ia - b.x * ib + EPSF;
  float d1 = a.y * ia - b.y * ib + EPSF;
  float d2 = a.z * ia - b.z * ib + EPSF;
  float d3 = a.w * ia - b.w * ib + EPSF;
  float ss = d0 * d0 + d1 * d1 + d2 * d2 + d3 * d3;
#pragma unroll
  for (int o = 32; o > 0; o >>= 1) ss += __shfl_down(ss, o, 64);
  __shared__ float red[4];
  if ((t & 63) == 0) red[t >> 6] = ss;
  __syncthreads();
  if (t == 0) {
    float s = red[0] + red[1] + red[2] + red[3];
    part[row] = logf(sqrtf(s) + EPSF);
  }
}

// ---------------- kernel 4: final reduce (no atomics) ----------------
__global__ __launch_bounds__(1024)
void k_final(const float* __restrict__ part, float* __restrict__ out) {
  int t = threadIdx.x;
  float s = 0.0f;
#pragma unroll
  for (int i = 0; i < N / 1024; ++i) s += part[t + i * 1024];
#pragma unroll
  for (int o = 32; o > 0; o >>= 1) s += __shfl_down(s, o, 64);
  __shared__ float red[16];
  if ((t & 63) == 0) red[t >> 6] = s;
  __syncthreads();
  if (t == 0) {
    float tot = 0.0f;
#pragma unroll
    for (int i = 0; i < 16; ++i) tot += red[i];
    out[0] = -tot / (float)N;
  }
}

extern "C" void kernel_launch(void* const* d_in, const int* in_sizes, int n_in,
                              void* d_out, int out_size, void* d_ws, size_t ws_size,
                              hipStream_t stream) {
  const float* x = (const float*)d_in[0];
  float* out = (float*)d_out;
  char* ws = (char*)d_ws;
  unsigned short* xb = (unsigned short*)(ws + XB_OFF);
  float* invn = (float*)(ws + INV_OFF);
  unsigned long long* keys = (unsigned long long*)(ws + KEY_OFF);
  float* part = (float*)(ws + PART_OFF);

  // allow 64 KiB dynamic LDS (idempotent; not a stream op, graph-capture-safe)
  (void)hipFuncSetAttribute((const void*)k_sim,
                            hipFuncAttributeMaxDynamicSharedMemorySize, 65536);

  k_norm<<<N, 256, 0, stream>>>(x, xb, invn, keys);
  k_sim<<<NTRI, 512, 65536, stream>>>(xb, keys);
  k_dist<<<N, 256, 0, stream>>>(x, invn, keys, part);
  k_final<<<1, 1024, 0, stream>>>(part, out);
}

// Round 13
// 234.574 us; speedup vs baseline: 5.4114x; 5.4114x over previous
//
#include <hip/hip_runtime.h>
#include <stdint.h>

#define N 8192
#define DIM 1024
#define EPSF 1e-8f
#define NBLK 32           // 8192/256
#define NTRI 528          // NBLK*(NBLK+1)/2
#define KT 16             // K-tiles of 64: 1024/64

typedef __attribute__((ext_vector_type(4))) float f32x4;
typedef __attribute__((ext_vector_type(8))) short s16x8;

// ---- helpers ----
__device__ inline unsigned short f2bf(float f) {
  unsigned u = __float_as_uint(f);
  unsigned r = (u + 0x7FFFu + ((u >> 16) & 1u)) >> 16;
  return (unsigned short)r;
}

__device__ inline unsigned encf(float f) {
  unsigned u = __float_as_uint(f);
  return (u & 0x80000000u) ? ~u : (u | 0x80000000u);
}

// ws layout:
//   [0, 16MiB)       : xb   bf16 normalized rows, row-major 8192x1024 (ushort)
//   [16777216,+32KiB): invn fp32 per-row 1/max(norm,eps)
//   [16809984,+64KiB): keys u64 packed (enc(sim)<<32)|~col
//   [16875520,+32KiB): part fp32 per-row log(dist+eps)
#define XB_OFF   0
#define INV_OFF  16777216
#define KEY_OFF  16809984
#define PART_OFF 16875520

// ---------------- kernel 1: normalize + init ----------------
__global__ __launch_bounds__(256)
void k_norm(const float* __restrict__ x, unsigned short* __restrict__ xb,
            float* __restrict__ invn, unsigned long long* __restrict__ keys) {
  int row = blockIdx.x, t = threadIdx.x;
  const float4* xr = (const float4*)(x + (size_t)row * DIM);
  float4 v = xr[t];
  float ss = v.x * v.x + v.y * v.y + v.z * v.z + v.w * v.w;
#pragma unroll
  for (int o = 32; o > 0; o >>= 1) ss += __shfl_down(ss, o, 64);
  __shared__ float red[4];
  __shared__ float sinv;
  if ((t & 63) == 0) red[t >> 6] = ss;
  __syncthreads();
  if (t == 0) {
    float s = red[0] + red[1] + red[2] + red[3];
    float inv = 1.0f / fmaxf(sqrtf(s), EPSF);
    sinv = inv;
    invn[row] = inv;
    keys[row] = 0ull;           // any sim >= -1 encodes > 0
  }
  __syncthreads();
  float inv = sinv;
  ushort4 o4;
  o4.x = f2bf(v.x * inv);
  o4.y = f2bf(v.y * inv);
  o4.z = f2bf(v.z * inv);
  o4.w = f2bf(v.w * inv);
  ((ushort4*)(xb + (size_t)row * DIM))[t] = o4;
}

// ---------------- kernel 2: sim GEMM + argmax (256^2, BK=64, 4-quadrant-phase) ----------------
// m201-style 8-phase-per-2-K-tiles schedule, plain HIP. 512 thr = 8 waves (2Mx4N),
// per-wave 128x64 out. LDS 2-buf x (256x64) x {A,B} = 128 KiB -> 1 block/CU (by design:
// m201 proves 62% MfmaUtil with 1 block/CU; overlap is INTRA-block via phases).
// Per K-tile t (buf c=t&1): 4 phases, each {ds_reads of one quadrant's new frags;
// stage-issue for t+1 into buf c^1; s_barrier; setprio1; 16 MFMA; setprio0; s_barrier}.
// Stages spread over phases 1-3 (A01 / B0 / B1), so the single end-of-tile vmcnt(0)
// waits on loads >=1.5 phases (~800cy) old -> nearly free (T4 mechanism).
// Swizzle (T2): row stride 128B; phys 16B-chunk p = c ^ (r&7) both on gload source
// and ds_read -> 0 bank conflicts (verified rounds 3-10).
// Ledger: stage(t+1) writes buf c^1, last read at tile t-1, whose reads retired
// before t-1's final barrier. vmcnt(0)+barrier at end of t proves t+1 staged.
// NOTE __launch_bounds__(512) with NO min-waves clause: (512,4) forced a 128-reg
// cap -> acc spilled to scratch -> 2.4GB scratch writes, 7.7x slower (round 10).
__global__ __launch_bounds__(512)
void k_sim(const unsigned short* __restrict__ xb, unsigned long long* __restrict__ keys) {
  extern __shared__ unsigned short lds_us[];  // A: [buf][16384), B: 32768 + [buf][16384)

  int b = blockIdx.x;
  int bi = (int)((65.0f - sqrtf(4225.0f - 8.0f * (float)b)) * 0.5f);
  while ((bi + 1) * (65 - (bi + 1)) / 2 <= b) ++bi;
  while (bi * (65 - bi) / 2 > b) --bi;
  int bj = bi + (b - bi * (65 - bi) / 2);

  const int t = threadIdx.x, lane = t & 63, wv = t >> 6;
  const int wr = wv >> 2, wc = wv & 3;       // wave -> (2M x 4N) grid
  const int hi = lane >> 4, lo = lane & 15;
  const int rowBase = bi * 256, colBase = bj * 256;

  const unsigned short* gA = xb + (size_t)rowBase * DIM;
  const unsigned short* gB = xb + (size_t)colBase * DIM;

  // ---- staging constants (per thread) ----
  // half-tile = 128 rows x 64 cols x 2B = 16KB = 512 thr x 2 loads x 16B.
  // load j covers rows j*64 + (t>>3), phys chunk t&7; source logical chunk
  // = (t&7) ^ (row&7); row&7 == (t>>3)&7 for both j (64%8==0).
  const int srow = t >> 3;
  const int schunk = (t & 7) ^ (srow & 7);
  const size_t so0 = (size_t)srow * DIM + schunk * 8;          // j=0
  const size_t so1 = (size_t)(64 + srow) * DIM + schunk * 8;   // j=1
  const int ld0 = t * 8;            // LDS ushort offset within half, j=0
  const int ld1 = 4096 + t * 8;     // j=1

// stage one operand's half h of K-tile T into buf NB. OPLDS = 0 (A) or 32768 (B)
#define STAGE_HALF(GP, OPLDS, NB, H, T_) do {                                        \
    const size_t gbase = (size_t)(H) * 128 * DIM + (size_t)(T_) * 64;                \
    unsigned short* lb = lds_us + (OPLDS) + (NB) * 16384 + (H) * 8192;               \
    __builtin_amdgcn_global_load_lds(                                                \
        (const __attribute__((address_space(1))) void*)(GP + gbase + so0),           \
        (__attribute__((address_space(3))) void*)(lb + ld0), 16, 0, 0);              \
    __builtin_amdgcn_global_load_lds(                                                \
        (const __attribute__((address_space(1))) void*)(GP + gbase + so1),           \
        (__attribute__((address_space(3))) void*)(lb + ld1), 16, 0, 0);              \
  } while (0)

  const f32x4 fzero = {0.f, 0.f, 0.f, 0.f};
  f32x4 acc[8][4];
#pragma unroll
  for (int i = 0; i < 8; ++i)
#pragma unroll
    for (int j = 0; j < 4; ++j) acc[i][j] = fzero;

  // fragment read: row r (stride 64 ushorts), chunk c = (kk*4+hi) ^ (lo&7)
  const int l7 = lo & 7;

#define RD(BASE_, R_, KK_) (*(const s16x8*)(lds_us + (BASE_) + (R_) * 64 + ((((KK_) << 2) | hi) ^ l7) * 8))

#define BAR __builtin_amdgcn_s_barrier()

// one K-tile: CB = buf (const), T_ = tile index, DS = 1 to stage tile T_+1
#define TILE(CB, T_, DS) do {                                                        \
    const int Ab = (CB) * 16384, Bb = 32768 + (CB) * 16384, NB = (CB) ^ 1;           \
    s16x8 af[4][2], b01[2][2], b23[2][2];                                            \
    /* ---- phase 1: Q(mi0-3, ni0-1) ---- */                                         \
    _Pragma("unroll") for (int mi = 0; mi < 4; ++mi)                                 \
      _Pragma("unroll") for (int kk = 0; kk < 2; ++kk)                               \
        af[mi][kk] = RD(Ab, wr * 128 + mi * 16 + lo, kk);                            \
    _Pragma("unroll") for (int ni = 0; ni < 2; ++ni)                                 \
      _Pragma("unroll") for (int kk = 0; kk < 2; ++kk)                               \
        b01[ni][kk] = RD(Bb, wc * 64 + ni * 16 + lo, kk);                            \
    if (DS) { STAGE_HALF(gA, 0, NB, 0, (T_) + 1); STAGE_HALF(gA, 0, NB, 1, (T_) + 1); } \
    BAR;                                                                             \
    __builtin_amdgcn_s_setprio(1);                                                   \
    _Pragma("unroll") for (int mi = 0; mi < 4; ++mi)                                 \
      _Pragma("unroll") for (int ni = 0; ni < 2; ++ni)                               \
        _Pragma("unroll") for (int kk = 0; kk < 2; ++kk)                             \
          acc[mi][ni] = __builtin_amdgcn_mfma_f32_16x16x32_bf16(af[mi][kk], b01[ni][kk], acc[mi][ni], 0, 0, 0); \
    __builtin_amdgcn_s_setprio(0);                                                   \
    BAR;                                                                             \
    /* ---- phase 2: Q(mi0-3, ni2-3) ---- */                                         \
    _Pragma("unroll") for (int ni = 0; ni < 2; ++ni)                                 \
      _Pragma("unroll") for (int kk = 0; kk < 2; ++kk)                               \
        b23[ni][kk] = RD(Bb, wc * 64 + (ni + 2) * 16 + lo, kk);                      \
    if (DS) STAGE_HALF(gB, 32768, NB, 0, (T_) + 1);                                  \
    BAR;                                                                             \
    __builtin_amdgcn_s_setprio(1);                                                   \
    _Pragma("unroll") for (int mi = 0; mi < 4; ++mi)                                 \
      _Pragma("unroll") for (int ni = 0; ni < 2; ++ni)                               \
        _Pragma("unroll") for (int kk = 0; kk < 2; ++kk)                             \
          acc[mi][ni + 2] = __builtin_amdgcn_mfma_f32_16x16x32_bf16(af[mi][kk], b23[ni][kk], acc[mi][ni + 2], 0, 0, 0); \
    __builtin_amdgcn_s_setprio(0);                                                   \
    BAR;                                                                             \
    /* ---- phase 3: Q(mi4-7, ni2-3) ---- */                                         \
    _Pragma("unroll") for (int mi = 0; mi < 4; ++mi)                                 \
      _Pragma("unroll") for (int kk = 0; kk < 2; ++kk)                               \
        af[mi][kk] = RD(Ab, wr * 128 + (mi + 4) * 16 + lo, kk);                      \
    if (DS) STAGE_HALF(gB, 32768, NB, 1, (T_) + 1);                                  \
    BAR;                                                                             \
    __builtin_amdgcn_s_setprio(1);                                                   \
    _Pragma("unroll") for (int mi = 0; mi < 4; ++mi)                                 \
      _Pragma("unroll") for (int ni = 0; ni < 2; ++ni)                               \
        _Pragma("unroll") for (int kk = 0; kk < 2; ++kk)                             \
          acc[mi + 4][ni + 2] = __builtin_amdgcn_mfma_f32_16x16x32_bf16(af[mi][kk], b23[ni][kk], acc[mi + 4][ni + 2], 0, 0, 0); \
    __builtin_amdgcn_s_setprio(0);                                                   \
    BAR;                                                                             \
    /* ---- phase 4: Q(mi4-7, ni0-1), no new reads ---- */                           \
    __builtin_amdgcn_s_setprio(1);                                                   \
    _Pragma("unroll") for (int mi = 0; mi < 4; ++mi)                                 \
      _Pragma("unroll") for (int ni = 0; ni < 2; ++ni)                               \
        _Pragma("unroll") for (int kk = 0; kk < 2; ++kk)                             \
          acc[mi + 4][ni] = __builtin_amdgcn_mfma_f32_16x16x32_bf16(af[mi][kk], b01[ni][kk], acc[mi + 4][ni], 0, 0, 0); \
    __builtin_amdgcn_s_setprio(0);                                                   \
    asm volatile("s_waitcnt vmcnt(0)" ::: "memory");  /* t+1 loads >=1.5 phases old */ \
    BAR;                                                                             \
  } while (0)

  // ---- prologue: stage tile 0 into buf 0 ----
  STAGE_HALF(gA, 0, 0, 0, 0); STAGE_HALF(gA, 0, 0, 1, 0);
  STAGE_HALF(gB, 32768, 0, 0, 0); STAGE_HALF(gB, 32768, 0, 1, 0);
  asm volatile("s_waitcnt vmcnt(0)" ::: "memory");
  BAR;

  // ---- main: tiles 0..13 (const bufs), peel 14,15 ----
  for (int kb = 0; kb < 14; kb += 2) {
    TILE(0, kb, 1);
    TILE(1, kb + 1, 1);
  }
  TILE(0, 14, 1);   // stages tile 15
  TILE(1, 15, 0);   // last tile, no stage

#undef TILE
#undef RD
#undef BAR
#undef STAGE_HALF

  // ---- per-row argmax (C layout: col=lane&15, row=(lane>>4)*4+reg) ----
#pragma unroll
  for (int am = 0; am < 8; ++am) {
#pragma unroll
    for (int reg = 0; reg < 4; ++reg) {
      int grow = rowBase + wr * 128 + am * 16 + hi * 4 + reg;
      float best = -10.0f;
      int bcol = 0;
#pragma unroll
      for (int ni = 0; ni < 4; ++ni) {
        int gcol = colBase + wc * 64 + ni * 16 + lo;
        float v = acc[am][ni][reg];
        v = (gcol == grow) ? -10.0f : v;   // mask diagonal
        if (v > best || (v == best && gcol < bcol)) { best = v; bcol = gcol; }
      }
#pragma unroll
      for (int m = 1; m < 16; m <<= 1) {
        float ov = __shfl_xor(best, m, 64);
        int oc = __shfl_xor(bcol, m, 64);
        if (ov > best || (ov == best && oc < bcol)) { best = ov; bcol = oc; }
      }
      if (lo == 0) {
        unsigned long long key = ((unsigned long long)encf(best) << 32) | (unsigned)(~bcol);
        atomicMax(&keys[grow], key);
      }
    }
  }

  // ---- per-col argmax (symmetric contribution), off-diagonal blocks only ----
  if (bi != bj) {
#pragma unroll
    for (int ni = 0; ni < 4; ++ni) {
      int gcol = colBase + wc * 64 + ni * 16 + lo;
      float best = -10.0f;
      int brow = 0;
#pragma unroll
      for (int am = 0; am < 8; ++am)
#pragma unroll
        for (int reg = 0; reg < 4; ++reg) {
          int grow = rowBase + wr * 128 + am * 16 + hi * 4 + reg;
          float v = acc[am][ni][reg];
          if (v > best || (v == best && grow < brow)) { best = v; brow = grow; }
        }
#pragma unroll
      for (int m = 16; m < 64; m <<= 1) {
        float ov = __shfl_xor(best, m, 64);
        int oc = __shfl_xor(brow, m, 64);
        if (ov > best || (ov == best && oc < brow)) { best = ov; brow = oc; }
      }
      if (hi == 0) {
        unsigned long long key = ((unsigned long long)encf(best) << 32) | (unsigned)(~brow);
        atomicMax(&keys[gcol], key);
      }
    }
  }
}

// ---------------- kernel 3: exact fp32 distance -> per-row partial ----------------
__global__ __launch_bounds__(256)
void k_dist(const float* __restrict__ x, const float* __restrict__ invn,
            const unsigned long long* __restrict__ keys, float* __restrict__ part) {
  int row = blockIdx.x, t = threadIdx.x;
  unsigned long long key = keys[row];
  int nb = (int)(~(unsigned)key);       // decode ~col
  float ia = invn[row], ib = invn[nb];
  float4 a = ((const float4*)(x + (size_t)row * DIM))[t];
  float4 b = ((const float4*)(x + (size_t)nb * DIM))[t];
  float d0 = a.x * ia - b.x * ib + EPSF;
  float d1 = a.y * ia - b.y * ib + EPSF;
  float d2 = a.z * ia - b.z * ib + EPSF;
  float d3 = a.w * ia - b.w * ib + EPSF;
  float ss = d0 * d0 + d1 * d1 + d2 * d2 + d3 * d3;
#pragma unroll
  for (int o = 32; o > 0; o >>= 1) ss += __shfl_down(ss, o, 64);
  __shared__ float red[4];
  if ((t & 63) == 0) red[t >> 6] = ss;
  __syncthreads();
  if (t == 0) {
    float s = red[0] + red[1] + red[2] + red[3];
    part[row] = logf(sqrtf(s) + EPSF);
  }
}

// ---------------- kernel 4: final reduce (no atomics) ----------------
__global__ __launch_bounds__(1024)
void k_final(const float* __restrict__ part, float* __restrict__ out) {
  int t = threadIdx.x;
  float s = 0.0f;
#pragma unroll
  for (int i = 0; i < N / 1024; ++i) s += part[t + i * 1024];
#pragma unroll
  for (int o = 32; o > 0; o >>= 1) s += __shfl_down(s, o, 64);
  __shared__ float red[16];
  if ((t & 63) == 0) red[t >> 6] = s;
  __syncthreads();
  if (t == 0) {
    float tot = 0.0f;
#pragma unroll
    for (int i = 0; i < 16; ++i) tot += red[i];
    out[0] = -tot / (float)N;
  }
}

extern "C" void kernel_launch(void* const* d_in, const int* in_sizes, int n_in,
                              void* d_out, int out_size, void* d_ws, size_t ws_size,
                              hipStream_t stream) {
  const float* x = (const float*)d_in[0];
  float* out = (float*)d_out;
  char* ws = (char*)d_ws;
  unsigned short* xb = (unsigned short*)(ws + XB_OFF);
  float* invn = (float*)(ws + INV_OFF);
  unsigned long long* keys = (unsigned long long*)(ws + KEY_OFF);
  float* part = (float*)(ws + PART_OFF);

  // allow 128 KiB dynamic LDS (idempotent; not a stream op, graph-capture-safe)
  (void)hipFuncSetAttribute((const void*)k_sim,
                            hipFuncAttributeMaxDynamicSharedMemorySize, 131072);

  k_norm<<<N, 256, 0, stream>>>(x, xb, invn, keys);
  k_sim<<<NTRI, 512, 131072, stream>>>(xb, keys);
  k_dist<<<N, 256, 0, stream>>>(x, invn, keys, part);
  k_final<<<1, 1024, 0, stream>>>(part, out);
}